// Round 2
// baseline (1839.762 us; speedup 1.0000x reference)
//
#include <hip/hip_runtime.h>
#include <hip/hip_bf16.h>
#include <cstdint>

#define NN    50000
#define NE    1600000
#define NG    512
#define F     64        // ATOM_FEA
#define ED    32        // EDGE_DIM
#define ZIN   160       // 2F + ED
#define NC    128       // fused Wf|Ws output cols
#define HF    128       // H_FEA
#define NCONV 3
#define BN_EPS 1e-5f
#define AS    168       // LDS row stride (bf16 elems), 16B-aligned, 2-way-conflict only

typedef __bf16 bf16_t;
typedef bf16_t bf16x8 __attribute__((ext_vector_type(8)));
typedef float  f32x16 __attribute__((ext_vector_type(16)));

__device__ __forceinline__ bf16x8 lds_load8(const bf16_t* p, int idx) {
  union { uint2 u[2]; bf16x8 v; } t;
  t.u[0] = *(const uint2*)(p + idx);
  t.u[1] = *(const uint2*)(p + idx + 8);
  return t.v;
}

__global__ void k_embed(const int* __restrict__ x, const float* __restrict__ emb,
                        float* __restrict__ h32, bf16_t* __restrict__ hb) {
  int i = blockIdx.x * 256 + threadIdx.x;
  if (i >= NN * F) return;
  int node = i >> 6, c = i & 63;
  float v = emb[x[node] * F + c];
  h32[i] = v;
  hb[i] = (bf16_t)v;
}

__global__ void k_wprep(const float* __restrict__ Wf, const float* __restrict__ Ws,
                        bf16_t* __restrict__ Wt) {
  int i = blockIdx.x * 256 + threadIdx.x;  // NCONV*ZIN*NC = 61440
  if (i >= NCONV * ZIN * NC) return;
  int l = i / (ZIN * NC), r = i % (ZIN * NC), k = r / NC, c = r % NC;
  float v = (c < F) ? Wf[(l * ZIN + k) * F + c] : Ws[(l * ZIN + k) * F + (c - F)];
  Wt[(l * NC + c) * ZIN + k] = (bf16_t)v;   // transposed: Wt[l][c][k]
}

// ---- counting sort by dst ----
__global__ void k_hist(const int* __restrict__ ei, int* __restrict__ cnt) {
  int e = blockIdx.x * 256 + threadIdx.x;
  if (e < NE) atomicAdd(&cnt[ei[NE + e]], 1);
}

__global__ void k_scan(const int* __restrict__ cnt, int* __restrict__ off) {
  __shared__ int ts[1024];
  const int t = threadIdx.x;
  const int CH = 49;                 // 1024*49 = 50176 >= NN
  const int base = t * CH;
  int s = 0;
  for (int i = 0; i < CH; ++i) { int idx = base + i; if (idx < NN) s += cnt[idx]; }
  ts[t] = s;
  __syncthreads();
  for (int d = 1; d < 1024; d <<= 1) {
    int v = (t >= d) ? ts[t - d] : 0;
    __syncthreads();
    ts[t] += v;
    __syncthreads();
  }
  int run = (t == 0) ? 0 : ts[t - 1];
  for (int i = 0; i < CH; ++i) {
    int idx = base + i;
    if (idx < NN) { off[idx] = run; run += cnt[idx]; }
  }
}

__global__ void k_scatter(const int* __restrict__ ei, const float* __restrict__ ea,
                          int* __restrict__ head, int* __restrict__ srcs,
                          int* __restrict__ dsts, bf16_t* __restrict__ eas) {
  int e = blockIdx.x * 256 + threadIdx.x;
  if (e >= NE) return;
  int d = ei[NE + e], s = ei[e];
  int p = atomicAdd(&head[d], 1);
  dsts[p] = d; srcs[p] = s;
  const float* pa = ea + (size_t)e * ED;
  bf16_t* pe = eas + (size_t)p * ED;
  #pragma unroll
  for (int q = 0; q < ED; q += 8) {
    float4 x0 = *(const float4*)(pa + q), x1 = *(const float4*)(pa + q + 4);
    union { bf16_t h[8]; uint4 u; } pk;
    pk.h[0] = (bf16_t)x0.x; pk.h[1] = (bf16_t)x0.y; pk.h[2] = (bf16_t)x0.z; pk.h[3] = (bf16_t)x0.w;
    pk.h[4] = (bf16_t)x1.x; pk.h[5] = (bf16_t)x1.y; pk.h[6] = (bf16_t)x1.z; pk.h[7] = (bf16_t)x1.w;
    *(uint4*)(pe + q) = pk.u;
  }
}

__launch_bounds__(256, 1)
__global__ void k_edges(const int* __restrict__ srcs, const int* __restrict__ dsts,
                        const bf16_t* __restrict__ eas, const bf16_t* __restrict__ hb,
                        const bf16_t* __restrict__ Wt,
                        const float* __restrict__ bfv, const float* __restrict__ bsv,
                        float* __restrict__ agg, int layer) {
  extern __shared__ char smem[];
  bf16_t* Ash  = (bf16_t*)smem;                            // [256][AS] z-tile (86016 B)
  bf16_t* Bsh  = (bf16_t*)(smem + 256 * AS * 2);           // [128][AS] W^T (43008 B)
  int*    dstT = (int*)(smem + 256 * AS * 2 + 128 * AS * 2);
  int*    srcT = dstT + 256;
  float*  mL   = (float*)smem;                             // reuses Ash after compute: [256][64]

  const int tid = threadIdx.x;
  const int e0  = blockIdx.x * 256;

  dstT[tid] = dsts[e0 + tid];
  srcT[tid] = srcs[e0 + tid];

  // stage W^T for this layer
  const bf16_t* W = Wt + layer * NC * ZIN;
  for (int i = tid; i < (NC * ZIN) / 8; i += 256) {
    int c = i / (ZIN / 8), kk = (i % (ZIN / 8)) * 8;
    *(uint4*)(Bsh + c * AS + kk) = *(const uint4*)(W + c * ZIN + kk);
  }
  __syncthreads();

  // stage z = [h[dst] || h[src] || eas] as bf16
  for (int i = tid; i < 256 * 8; i += 256) {
    int e = i >> 3, q = (i & 7) * 8;
    *(uint4*)(Ash + e * AS + q) = *(const uint4*)(hb + (size_t)dstT[e] * F + q);
  }
  for (int i = tid; i < 256 * 8; i += 256) {
    int e = i >> 3, q = (i & 7) * 8;
    *(uint4*)(Ash + e * AS + F + q) = *(const uint4*)(hb + (size_t)srcT[e] * F + q);
  }
  for (int i = tid; i < 256 * 4; i += 256) {
    int e = i >> 2, q = (i & 3) * 8;
    *(uint4*)(Ash + e * AS + 2 * F + q) = *(const uint4*)(eas + (size_t)(e0 + e) * ED + q);
  }
  __syncthreads();

  const int w  = tid >> 6;   // wave id: edges [w*64, w*64+64)
  const int l  = tid & 63;
  const int lr = l & 31;
  const int g  = l >> 5;

  f32x16 acc[2][4] = {};

  #pragma unroll 2
  for (int ks = 0; ks < 10; ++ks) {
    const int k0 = ks * 16;
    bf16x8 af[2], bf8[4];
    #pragma unroll
    for (int r = 0; r < 2; ++r)
      af[r] = lds_load8(Ash, (w * 64 + r * 32 + lr) * AS + k0 + g * 4);
    #pragma unroll
    for (int n = 0; n < 4; ++n)
      bf8[n] = lds_load8(Bsh, (n * 32 + lr) * AS + k0 + g * 4);
    #pragma unroll
    for (int r = 0; r < 2; ++r)
      #pragma unroll
      for (int n = 0; n < 4; ++n)
        acc[r][n] = __builtin_amdgcn_mfma_f32_32x32x16_bf16(af[r], bf8[n], acc[r][n], 0, 0, 0);
  }

  __syncthreads();   // all waves done reading Ash/Bsh before mL overwrites

  // epilogue: m = sigmoid(f + bf) * softplus(s + bs) -> LDS f32 [256][64]
  const float* bfl = bfv + layer * F;
  const float* bsl = bsv + layer * F;
  #pragma unroll
  for (int r = 0; r < 2; ++r) {
    #pragma unroll
    for (int n = 0; n < 2; ++n) {
      const int c = n * 32 + lr;
      const float bfc = bfl[c], bsc = bsl[c];
      f32x16 vf = acc[r][n], vs = acc[r][n + 2];
      #pragma unroll
      for (int q = 0; q < 16; ++q) {
        int row = (q & 3) + 8 * (q >> 2) + 4 * g;   // verified 32x32 C/D row map
        int e = w * 64 + r * 32 + row;
        float fv = vf[q] + bfc;
        float sv = vs[q] + bsc;
        float sig = 1.0f / (1.0f + __expf(-fv));
        float sp  = (sv > 20.0f) ? sv : __logf(1.0f + __expf(sv));
        mL[e * 64 + c] = sig * sp;
      }
    }
  }
  __syncthreads();

  // segmented reduction over sorted-dst runs: one atomic per (run, col, quarter)
  {
    const int c = tid & 63;
    const int q = tid >> 6;
    const int i0 = q * 64, i1 = i0 + 64;
    float r = mL[i0 * 64 + c];
    int cur = dstT[i0];
    for (int i = i0 + 1; i < i1; ++i) {
      int d2 = dstT[i];
      float v = mL[i * 64 + c];
      if (d2 != cur) {
        atomicAdd(agg + (size_t)cur * F + c, r);
        r = v; cur = d2;
      } else {
        r += v;
      }
    }
    atomicAdd(agg + (size_t)cur * F + c, r);
  }
}

__global__ void k_update(const float* __restrict__ agg, const float* __restrict__ gam,
                         const float* __restrict__ bet, const float* __restrict__ mu,
                         const float* __restrict__ var, float* __restrict__ h32,
                         bf16_t* __restrict__ hb, int layer) {
  int i = blockIdx.x * 256 + threadIdx.x;
  if (i >= NN * F) return;
  int c = i & 63;
  float sc = gam[layer * F + c] * rsqrtf(var[layer * F + c] + BN_EPS);
  float sh = bet[layer * F + c] - mu[layer * F + c] * sc;
  float v = agg[i] * sc + sh + h32[i];
  v = fmaxf(v, 0.0f);
  h32[i] = v;
  hb[i] = (bf16_t)v;
}

__device__ __forceinline__ int lowb(const int* a, int n, int v) {
  int lo = 0, hi = n;
  while (lo < hi) { int mid = (lo + hi) >> 1; if (a[mid] < v) lo = mid + 1; else hi = mid; }
  return lo;
}

__global__ void k_pool_mlp(const float* __restrict__ h32, const int* __restrict__ batch,
                           const float* __restrict__ W1, const float* __restrict__ b1,
                           const float* __restrict__ W2, const float* __restrict__ b2,
                           float* __restrict__ out) {
  __shared__ float pooled[F];
  __shared__ float ps[HF];
  __shared__ float red[HF];
  const int gph = blockIdx.x;
  const int t = threadIdx.x;   // 128 threads
  const int lo = lowb(batch, NN, gph);
  const int hi = lowb(batch, NN, gph + 1);

  float s = 0.f;
  for (int i = lo + (t >> 6); i < hi; i += 2) s += h32[(size_t)i * F + (t & 63)];
  ps[t] = s;
  __syncthreads();
  if (t < F) {
    float tot = ps[t] + ps[t + F];
    pooled[t] = tot / fmaxf((float)(hi - lo), 1.0f);
  }
  __syncthreads();

  float a = b1[t];
  for (int c = 0; c < F; ++c) a += pooled[c] * W1[c * HF + t];
  a = fmaxf(a, 0.f);
  red[t] = a * W2[t];
  __syncthreads();
  for (int sdv = 64; sdv > 0; sdv >>= 1) {
    if (t < sdv) red[t] += red[t + sdv];
    __syncthreads();
  }
  if (t == 0) out[gph] = red[0] + b2[0];
}

extern "C" void kernel_launch(void* const* d_in, const int* in_sizes, int n_in,
                              void* d_out, int out_size, void* d_ws, size_t ws_size,
                              hipStream_t stream) {
  const int*   x    = (const int*)d_in[0];
  const int*   ei   = (const int*)d_in[1];
  const float* ea   = (const float*)d_in[2];
  const int*   batch= (const int*)d_in[3];
  const float* emb  = (const float*)d_in[4];
  const float* Wf   = (const float*)d_in[5];
  const float* bfb  = (const float*)d_in[6];
  const float* Ws   = (const float*)d_in[7];
  const float* bsb  = (const float*)d_in[8];
  const float* gam  = (const float*)d_in[9];
  const float* bet  = (const float*)d_in[10];
  const float* mu   = (const float*)d_in[11];
  const float* var  = (const float*)d_in[12];
  const float* W1   = (const float*)d_in[13];
  const float* b1   = (const float*)d_in[14];
  const float* W2   = (const float*)d_in[15];
  const float* b2   = (const float*)d_in[16];
  float* out = (float*)d_out;

  char* p = (char*)d_ws;
  auto take = [&](size_t bytes) { char* q = p; p += (bytes + 255) & ~(size_t)255; return q; };
  float*  h32  = (float*)take((size_t)NN * F * 4);
  bf16_t* hb   = (bf16_t*)take((size_t)NN * F * 2);
  float*  agg  = (float*)take((size_t)NN * F * 4);
  bf16_t* Wt   = (bf16_t*)take((size_t)NCONV * NC * ZIN * 2);
  int*    cnt  = (int*)take((size_t)NN * 4);
  int*    off  = (int*)take((size_t)NN * 4);
  int*    head = (int*)take((size_t)NN * 4);
  int*    srcs = (int*)take((size_t)NE * 4);
  int*    dsts = (int*)take((size_t)NE * 4);
  bf16_t* eas  = (bf16_t*)take((size_t)NE * ED * 2);

  k_embed<<<(NN * F + 255) / 256, 256, 0, stream>>>(x, emb, h32, hb);
  k_wprep<<<(NCONV * ZIN * NC + 255) / 256, 256, 0, stream>>>(Wf, Ws, Wt);

  // counting sort by dst (invariant across layers; recomputed per call for determinism)
  hipMemsetAsync(cnt, 0, (size_t)NN * 4, stream);
  k_hist<<<(NE + 255) / 256, 256, 0, stream>>>(ei, cnt);
  k_scan<<<1, 1024, 0, stream>>>(cnt, off);
  hipMemcpyAsync(head, off, (size_t)NN * 4, hipMemcpyDeviceToDevice, stream);
  k_scatter<<<(NE + 255) / 256, 256, 0, stream>>>(ei, ea, head, srcs, dsts, eas);

  const size_t smem = 256 * AS * 2 + 128 * AS * 2 + 512 * 4;  // 131072 B
  hipFuncSetAttribute((const void*)k_edges, hipFuncAttributeMaxDynamicSharedMemorySize, (int)smem);

  for (int layer = 0; layer < NCONV; ++layer) {
    hipMemsetAsync(agg, 0, (size_t)NN * F * 4, stream);
    k_edges<<<NE / 256, 256, smem, stream>>>(srcs, dsts, eas, hb, Wt, bfb, bsb, agg, layer);
    k_update<<<(NN * F + 255) / 256, 256, 0, stream>>>(agg, gam, bet, mu, var, h32, hb, layer);
  }

  k_pool_mlp<<<NG, HF, 0, stream>>>(h32, batch, W1, b1, W2, b2, out);
}

// Round 3
// 842.246 us; speedup vs baseline: 2.1844x; 2.1844x over previous
//
#include <hip/hip_runtime.h>
#include <hip/hip_bf16.h>
#include <cstdint>

#define NN    50000
#define NE    1600000
#define NG    512
#define F     64        // ATOM_FEA
#define ED    32        // EDGE_DIM
#define ZIN   160       // 2F + ED
#define NC    128       // fused Wf|Ws output cols
#define HF    128       // H_FEA
#define NCONV 3
#define BN_EPS 1e-5f

typedef __bf16 bf16_t;
typedef bf16_t bf16x8 __attribute__((ext_vector_type(8)));
typedef float  f32x16 __attribute__((ext_vector_type(16)));

__global__ void k_embed(const int* __restrict__ x, const float* __restrict__ emb,
                        float* __restrict__ h32, bf16_t* __restrict__ hb) {
  int i = blockIdx.x * 256 + threadIdx.x;
  if (i >= NN * F) return;
  int node = i >> 6, c = i & 63;
  float v = emb[x[node] * F + c];
  h32[i] = v;
  hb[i] = (bf16_t)v;
}

// Wt layout: pre-fragmented for MFMA B-operand, per layer:
//   Wt[((l*10 + ks)*4 + n)*512 + lane*8 + idx]
//   lane: g=lane>>5, lr=lane&31; col c = n*32+lr; k = 16*ks + 4*g + 8*(idx>>2) + (idx&3)
__global__ void k_wprep(const float* __restrict__ Wf, const float* __restrict__ Ws,
                        bf16_t* __restrict__ Wt) {
  int i = blockIdx.x * 256 + threadIdx.x;  // NCONV*ZIN*NC = 61440
  if (i >= NCONV * ZIN * NC) return;
  int l = i / 20480, r = i % 20480;
  int ks = r / 2048, r2 = r % 2048;
  int n = r2 / 512, r3 = r2 % 512;
  int lane = r3 >> 3, idx = r3 & 7;
  int g = lane >> 5, lr = lane & 31;
  int c = n * 32 + lr;
  int k = 16 * ks + 4 * g + 8 * (idx >> 2) + (idx & 3);
  float v = (c < F) ? Wf[(l * ZIN + k) * F + c] : Ws[(l * ZIN + k) * F + (c - F)];
  Wt[i] = (bf16_t)v;
}

// ---- counting sort by dst ----
__global__ void k_hist(const int* __restrict__ ei, int* __restrict__ cnt) {
  int e = blockIdx.x * 256 + threadIdx.x;
  if (e < NE) atomicAdd(&cnt[ei[NE + e]], 1);
}

__global__ void k_scan(const int* __restrict__ cnt, int* __restrict__ off) {
  __shared__ int ts[1024];
  const int t = threadIdx.x;
  const int CH = 49;                 // 1024*49 = 50176 >= NN
  const int base = t * CH;
  int s = 0;
  for (int i = 0; i < CH; ++i) { int idx = base + i; if (idx < NN) s += cnt[idx]; }
  ts[t] = s;
  __syncthreads();
  for (int d = 1; d < 1024; d <<= 1) {
    int v = (t >= d) ? ts[t - d] : 0;
    __syncthreads();
    ts[t] += v;
    __syncthreads();
  }
  int run = (t == 0) ? 0 : ts[t - 1];
  for (int i = 0; i < CH; ++i) {
    int idx = base + i;
    if (idx < NN) { off[idx] = run; run += cnt[idx]; }
  }
}

__global__ void k_scatter(const int* __restrict__ ei, const float* __restrict__ ea,
                          int* __restrict__ head, int* __restrict__ srcs,
                          int* __restrict__ dsts, bf16_t* __restrict__ eas) {
  int e = blockIdx.x * 256 + threadIdx.x;
  if (e >= NE) return;
  int d = ei[NE + e], s = ei[e];
  int p = atomicAdd(&head[d], 1);
  dsts[p] = d; srcs[p] = s;
  const float* pa = ea + (size_t)e * ED;
  bf16_t* pe = eas + (size_t)p * ED;
  #pragma unroll
  for (int q = 0; q < ED; q += 8) {
    float4 x0 = *(const float4*)(pa + q), x1 = *(const float4*)(pa + q + 4);
    union { bf16_t h[8]; uint4 u; } pk;
    pk.h[0] = (bf16_t)x0.x; pk.h[1] = (bf16_t)x0.y; pk.h[2] = (bf16_t)x0.z; pk.h[3] = (bf16_t)x0.w;
    pk.h[4] = (bf16_t)x1.x; pk.h[5] = (bf16_t)x1.y; pk.h[6] = (bf16_t)x1.z; pk.h[7] = (bf16_t)x1.w;
    *(uint4*)(pe + q) = pk.u;
  }
}

// 512 threads, 8 waves, 256 edges/block (32/wave, one edge-row per lane pair)
// LDS: Bsh 40960 + mT 32768 + dstT 1024 = 74752 B -> 2 blocks/CU
__launch_bounds__(512, 4)
__global__ void k_edges(const int* __restrict__ srcs, const int* __restrict__ dsts,
                        const bf16_t* __restrict__ eas, const bf16_t* __restrict__ hb,
                        const bf16_t* __restrict__ Wt,
                        const float* __restrict__ bfv, const float* __restrict__ bsv,
                        float* __restrict__ agg, int layer) {
  extern __shared__ char smem[];
  bf16_t* Bsh  = (bf16_t*)smem;                       // [NC*ZIN] pre-fragmented
  bf16_t* mT   = (bf16_t*)(smem + 40960);             // [256][64] messages
  int*    dstT = (int*)(smem + 40960 + 32768);        // [256]

  const int tid = threadIdx.x;
  const int e0  = blockIdx.x * 256;

  // stage B: 40960 B = 2560 uint4, 5 per thread
  {
    const uint4* Wg = (const uint4*)(Wt + (size_t)layer * NC * ZIN);
    uint4* Bv = (uint4*)Bsh;
    #pragma unroll
    for (int t = 0; t < 5; ++t) Bv[tid + t * 512] = Wg[tid + t * 512];
  }
  if (tid < 256) dstT[tid] = dsts[e0 + tid];
  __syncthreads();

  const int w  = tid >> 6;
  const int l  = tid & 63;
  const int lr = l & 31;
  const int g  = l >> 5;
  const int e  = w * 32 + lr;

  const int dv = dstT[e];
  const int sv = srcs[e0 + e];

  // gather A-fragments straight from global (fragment layout: lane=row, 8B strided by g-half)
  const char* dp = (const char*)(hb + (size_t)dv * F);
  const char* sp = (const char*)(hb + (size_t)sv * F);
  const char* ep = (const char*)(eas + (size_t)(e0 + e) * ED);
  uint2 dq[8], sq[8], eq[4];
  #pragma unroll
  for (int j = 0; j < 8; ++j) dq[j] = *(const uint2*)(dp + (2 * j + g) * 8);
  #pragma unroll
  for (int j = 0; j < 8; ++j) sq[j] = *(const uint2*)(sp + (2 * j + g) * 8);
  #pragma unroll
  for (int j = 0; j < 4; ++j) eq[j] = *(const uint2*)(ep + (2 * j + g) * 8);

  f32x16 acc[4] = {};
  #pragma unroll
  for (int ks = 0; ks < 10; ++ks) {
    union { uint2 u[2]; bf16x8 v; } a;
    a.u[0] = (ks < 4) ? dq[2 * ks]     : (ks < 8) ? sq[2 * (ks - 4)]     : eq[2 * (ks - 8)];
    a.u[1] = (ks < 4) ? dq[2 * ks + 1] : (ks < 8) ? sq[2 * (ks - 4) + 1] : eq[2 * (ks - 8) + 1];
    #pragma unroll
    for (int n = 0; n < 4; ++n) {
      bf16x8 b = *(const bf16x8*)(Bsh + ((ks * 4 + n) * 64 + l) * 8);  // ds_read_b128, stride-1
      acc[n] = __builtin_amdgcn_mfma_f32_32x32x16_bf16(a.v, b, acc[n], 0, 0, 0);
    }
  }

  // epilogue: m = sigmoid(f+bf)*softplus(s+bs) -> bf16 mT (wave-private rows)
  const float* bfl = bfv + layer * F;
  const float* bsl = bsv + layer * F;
  bf16_t* mw = mT + w * 32 * F;
  #pragma unroll
  for (int n = 0; n < 2; ++n) {
    const int c = n * 32 + lr;
    const float bfc = bfl[c], bsc = bsl[c];
    #pragma unroll
    for (int q = 0; q < 16; ++q) {
      int row = (q & 3) + 8 * (q >> 2) + 4 * g;   // verified 32x32 C/D row map
      float fv = acc[n][q] + bfc;
      float sv2 = acc[n + 2][q] + bsc;
      float sig = 1.0f / (1.0f + __expf(-fv));
      float sp2 = (sv2 > 20.0f) ? sv2 : __logf(1.0f + __expf(sv2));
      mw[row * F + c] = (bf16_t)(sig * sp2);
    }
  }
  __syncthreads();

  // segmented reduction over sorted-dst runs: 8 segments x 64 cols
  {
    const int c = tid & 63;
    const int h0 = (tid >> 6) * 32;
    float r = (float)mT[h0 * F + c];
    int cur = dstT[h0];
    for (int i = h0 + 1; i < h0 + 32; ++i) {
      float v = (float)mT[i * F + c];
      int d2 = dstT[i];
      if (d2 != cur) {
        atomicAdd(agg + (size_t)cur * F + c, r);
        r = v; cur = d2;
      } else {
        r += v;
      }
    }
    atomicAdd(agg + (size_t)cur * F + c, r);
  }
}

__global__ void k_update(const float* __restrict__ agg, const float* __restrict__ gam,
                         const float* __restrict__ bet, const float* __restrict__ mu,
                         const float* __restrict__ var, float* __restrict__ h32,
                         bf16_t* __restrict__ hb, int layer) {
  int i = blockIdx.x * 256 + threadIdx.x;
  if (i >= NN * F) return;
  int c = i & 63;
  float sc = gam[layer * F + c] * rsqrtf(var[layer * F + c] + BN_EPS);
  float sh = bet[layer * F + c] - mu[layer * F + c] * sc;
  float v = agg[i] * sc + sh + h32[i];
  v = fmaxf(v, 0.0f);
  h32[i] = v;
  hb[i] = (bf16_t)v;
}

__device__ __forceinline__ int lowb(const int* a, int n, int v) {
  int lo = 0, hi = n;
  while (lo < hi) { int mid = (lo + hi) >> 1; if (a[mid] < v) lo = mid + 1; else hi = mid; }
  return lo;
}

__global__ void k_pool_mlp(const float* __restrict__ h32, const int* __restrict__ batch,
                           const float* __restrict__ W1, const float* __restrict__ b1,
                           const float* __restrict__ W2, const float* __restrict__ b2,
                           float* __restrict__ out) {
  __shared__ float pooled[F];
  __shared__ float ps[HF];
  __shared__ float red[HF];
  const int gph = blockIdx.x;
  const int t = threadIdx.x;   // 128 threads
  const int lo = lowb(batch, NN, gph);
  const int hi = lowb(batch, NN, gph + 1);

  float s = 0.f;
  for (int i = lo + (t >> 6); i < hi; i += 2) s += h32[(size_t)i * F + (t & 63)];
  ps[t] = s;
  __syncthreads();
  if (t < F) {
    float tot = ps[t] + ps[t + F];
    pooled[t] = tot / fmaxf((float)(hi - lo), 1.0f);
  }
  __syncthreads();

  float a = b1[t];
  for (int c = 0; c < F; ++c) a += pooled[c] * W1[c * HF + t];
  a = fmaxf(a, 0.f);
  red[t] = a * W2[t];
  __syncthreads();
  for (int sdv = 64; sdv > 0; sdv >>= 1) {
    if (t < sdv) red[t] += red[t + sdv];
    __syncthreads();
  }
  if (t == 0) out[gph] = red[0] + b2[0];
}

extern "C" void kernel_launch(void* const* d_in, const int* in_sizes, int n_in,
                              void* d_out, int out_size, void* d_ws, size_t ws_size,
                              hipStream_t stream) {
  const int*   x    = (const int*)d_in[0];
  const int*   ei   = (const int*)d_in[1];
  const float* ea   = (const float*)d_in[2];
  const int*   batch= (const int*)d_in[3];
  const float* emb  = (const float*)d_in[4];
  const float* Wf   = (const float*)d_in[5];
  const float* bfb  = (const float*)d_in[6];
  const float* Ws   = (const float*)d_in[7];
  const float* bsb  = (const float*)d_in[8];
  const float* gam  = (const float*)d_in[9];
  const float* bet  = (const float*)d_in[10];
  const float* mu   = (const float*)d_in[11];
  const float* var  = (const float*)d_in[12];
  const float* W1   = (const float*)d_in[13];
  const float* b1   = (const float*)d_in[14];
  const float* W2   = (const float*)d_in[15];
  const float* b2   = (const float*)d_in[16];
  float* out = (float*)d_out;

  char* p = (char*)d_ws;
  auto take = [&](size_t bytes) { char* q = p; p += (bytes + 255) & ~(size_t)255; return q; };
  float*  h32  = (float*)take((size_t)NN * F * 4);
  bf16_t* hb   = (bf16_t*)take((size_t)NN * F * 2);
  float*  agg  = (float*)take((size_t)NN * F * 4);
  bf16_t* Wt   = (bf16_t*)take((size_t)NCONV * NC * ZIN * 2);
  int*    cnt  = (int*)take((size_t)NN * 4);
  int*    off  = (int*)take((size_t)NN * 4);
  int*    head = (int*)take((size_t)NN * 4);
  int*    srcs = (int*)take((size_t)NE * 4);
  int*    dsts = (int*)take((size_t)NE * 4);
  bf16_t* eas  = (bf16_t*)take((size_t)NE * ED * 2);

  k_embed<<<(NN * F + 255) / 256, 256, 0, stream>>>(x, emb, h32, hb);
  k_wprep<<<(NCONV * ZIN * NC + 255) / 256, 256, 0, stream>>>(Wf, Ws, Wt);

  // counting sort by dst (invariant across layers)
  hipMemsetAsync(cnt, 0, (size_t)NN * 4, stream);
  k_hist<<<(NE + 255) / 256, 256, 0, stream>>>(ei, cnt);
  k_scan<<<1, 1024, 0, stream>>>(cnt, off);
  hipMemcpyAsync(head, off, (size_t)NN * 4, hipMemcpyDeviceToDevice, stream);
  k_scatter<<<(NE + 255) / 256, 256, 0, stream>>>(ei, ea, head, srcs, dsts, eas);

  const size_t smem = 40960 + 32768 + 1024;  // 74752 B -> 2 blocks/CU
  hipFuncSetAttribute((const void*)k_edges, hipFuncAttributeMaxDynamicSharedMemorySize, (int)smem);

  for (int layer = 0; layer < NCONV; ++layer) {
    hipMemsetAsync(agg, 0, (size_t)NN * F * 4, stream);
    k_edges<<<NE / 256, 512, smem, stream>>>(srcs, dsts, eas, hb, Wt, bfb, bsb, agg, layer);
    k_update<<<(NN * F + 255) / 256, 256, 0, stream>>>(agg, gam, bet, mu, var, h32, hb, layer);
  }

  k_pool_mlp<<<NG, HF, 0, stream>>>(h32, batch, W1, b1, W2, b2, out);
}